// Round 4
// baseline (525.698 us; speedup 1.0000x reference)
//
#include <hip/hip_runtime.h>

// Unfold (im2col) disguised as depthwise conv with eye(9) kernels.
// x: [16, 64, 112, 112] f32 -> out: [16, 64*9, 112, 112] f32
// out[n, c*9 + (kr*3+kc), h, w] = x[n, c, h+kr-1, w+kc-1] (zero pad)
//
// R7: DIAGNOSTIC PROBE (expected dur regression — buying counters).
// R3/R5/R6 all land at 2.6-2.8 TB/s effective while the harness fill
// writes this same buffer at 6.28 TB/s with plain stores; NT-vs-plain,
// read structure, and write-stream shape are all proven neutral. The
// kernel's own FETCH/WRITE/Occupancy counters have never been visible
// (it ranks below the ~295us fills in top-5). This probe repeats the
// idempotent store pass 3x so the kernel dispatch (~550us) enters the
// top-5 WITH counters. Discriminates:
//   P1 store-bound:  dur ~3x182=546, WRITE~1.39GB, FETCH small
//   P2 RFO:          FETCH_SIZE ~= WRITE_SIZE  (write-allocate reads)
//   P3 fixed/latency: dur ~182+2x75=330 (extra passes at fill rate)

#define NN 16
#define CC 64
#define HH 112
#define WW 112
#define W4C 28                 // float4 per row
#define PLANE4 (HH * W4C)      // 3136 float4 per output plane

typedef float v4f __attribute__((ext_vector_type(4)));

__global__ __launch_bounds__(256) void unfold9_probe(const float* __restrict__ x,
                                                     v4f* __restrict__ out,
                                                     unsigned total) {
    unsigned idx = blockIdx.x * 256u + threadIdx.x;
    if (idx >= total) return;

    unsigned w4 = idx % W4C;
    unsigned t  = idx / W4C;
    unsigned h  = t % HH;
    t /= HH;
    unsigned c  = t % CC;
    unsigned n  = t / CC;

    const float* __restrict__ xc = x + (((size_t)n * CC + c) * HH) * WW;
    unsigned wbase = w4 * 4u;

    v4f   mid[3];
    float lft[3], rgt[3];
#pragma unroll
    for (int kr = 0; kr < 3; ++kr) {
        int sh = (int)h + kr - 1;
        bool ok = (sh >= 0) && (sh < HH);
        const float* __restrict__ row = xc + (unsigned)(ok ? sh : 0) * WW;  // clamped
        v4f   m = *reinterpret_cast<const v4f*>(row + wbase);
        float l = (w4 > 0u)        ? row[wbase - 1u] : 0.f;
        float r = (w4 < W4C - 1u)  ? row[wbase + 4u] : 0.f;
        if (!ok) { m = (v4f){0.f, 0.f, 0.f, 0.f}; l = 0.f; r = 0.f; }
        mid[kr] = m; lft[kr] = l; rgt[kr] = r;
    }

    size_t base = ((size_t)n * (CC * 9) + (size_t)c * 9) * PLANE4
                + (size_t)h * W4C + w4;

    // Idempotent 3x store pass: identical correct values each rep.
    // asm memory barrier prevents dead-store elimination of reps 0,1.
#pragma unroll 1
    for (int rep = 0; rep < 3; ++rep) {
#pragma unroll
        for (int kr = 0; kr < 3; ++kr) {
            v4f m = mid[kr];
            v4f a = (v4f){lft[kr], m.x, m.y, m.z};   // kc=0: out[w] = x[w-1]
            v4f b = m;                               // kc=1: identity
            v4f d = (v4f){m.y, m.z, m.w, rgt[kr]};   // kc=2: out[w] = x[w+1]
            out[base + (size_t)(kr * 3 + 0) * PLANE4] = a;
            out[base + (size_t)(kr * 3 + 1) * PLANE4] = b;
            out[base + (size_t)(kr * 3 + 2) * PLANE4] = d;
        }
        asm volatile("" ::: "memory");
    }
}

extern "C" void kernel_launch(void* const* d_in, const int* in_sizes, int n_in,
                              void* d_out, int out_size, void* d_ws, size_t ws_size,
                              hipStream_t stream) {
    const float* x = (const float*)d_in[0];
    // d_in[1] (eye-kernel weight) is baked into the index math.
    v4f* out = (v4f*)d_out;

    const unsigned total = (unsigned)(NN * CC * HH * W4C);  // 3,211,264 threads
    const unsigned blocks = (total + 255u) / 256u;          // 12,544 blocks
    unfold9_probe<<<blocks, 256, 0, stream>>>(x, out, total);
}